// Round 20
// baseline (138.186 us; speedup 1.0000x reference)
//
#include <hip/hip_runtime.h>
#include <hip/hip_bf16.h>
#include <math.h>

#define H_DIM 128
#define W_DIM 128
#define BATCH 4
#define HW (H_DIM * W_DIM)

typedef __attribute__((ext_vector_type(8))) short bf16x8;
typedef __attribute__((ext_vector_type(4))) short s16x4;
typedef __attribute__((ext_vector_type(4))) float f32x4;
typedef __attribute__((ext_vector_type(4))) unsigned int u32x4;
typedef _Float16 f16x2 __attribute__((ext_vector_type(2)));
typedef _Float16 f16x8 __attribute__((ext_vector_type(8)));

static __device__ __forceinline__ unsigned short f2bf(float f) {
    __hip_bfloat16 h = __float2bfloat16(f);   // RNE
    return *reinterpret_cast<unsigned short*>(&h);
}
static __device__ __forceinline__ float bf2f(unsigned short u) {
    return __uint_as_float(((unsigned int)u) << 16);
}
static __device__ __forceinline__ unsigned short f2h(float f) {
    _Float16 h = (_Float16)f;                 // RNE
    return *reinterpret_cast<unsigned short*>(&h);
}

// ---------------------------------------------------------------------------
// Build swizzled-NHWC bf16 concat input [B][H][W][128]  AND  group-major
// nbr copy [B][8g][HW][8ch] in F16 (deform path is f16).
// ---------------------------------------------------------------------------
__global__ __launch_bounds__(256)
void prep_nhwc_kernel(const float* __restrict__ nbr, const float* __restrict__ ref,
                      unsigned short* __restrict__ dst,
                      unsigned short* __restrict__ gmaj) {
    __shared__ float s[128][65];   // 33.3 KB
    const int b  = blockIdx.y;
    const int p0 = blockIdx.x * 64;
    const int t  = threadIdx.x;
    const int px = t & 63;
#pragma unroll
    for (int it = 0; it < 32; ++it) {
        int c = it * 4 + (t >> 6);
        const float* src = (c < 64) ? nbr : ref;
        int cs = c & 63;
        s[c][px] = src[(size_t)(b * 64 + cs) * HW + p0 + px];
    }
    __syncthreads();
#pragma unroll
    for (int it = 0; it < 4; ++it) {
        int idx = it * 256 + t;
        int p  = idx >> 4;
        int ut = idx & 15;
        int x  = (p0 + p) & 127;
        int key = (x + 1) & 7;
        int cpos = (ut & 8) | ((ut & 7) ^ key);
        bf16x8 v;
#pragma unroll
        for (int j = 0; j < 8; ++j)
            v[j] = (short)f2bf(s[ut * 8 + j][p]);
        *(bf16x8*)(dst + ((size_t)(b * HW + p0 + p) * 128 + cpos * 8)) = v;
    }
#pragma unroll
    for (int it = 0; it < 2; ++it) {
        int idx = it * 256 + t;
        int g   = idx >> 6;
        int p2  = idx & 63;
        bf16x8 v;
#pragma unroll
        for (int j = 0; j < 8; ++j)
            v[j] = (short)f2h(s[g * 8 + j][p2]);     // f16!
        *(bf16x8*)(gmaj + ((size_t)(b * 8 + g) * HW + p0 + p2) * 8) = v;
    }
}

// ---------------------------------------------------------------------------
// ALL weight packs in one launch. wpkD is packed as F16 (deform path).
// ---------------------------------------------------------------------------
__global__ void pack_all_kernel(const float* __restrict__ w1, const float* __restrict__ w2,
                                const float* __restrict__ wom, const float* __restrict__ wdcn,
                                unsigned short* __restrict__ wpk1, unsigned short* __restrict__ wpk2,
                                unsigned short* __restrict__ wpk3, unsigned short* __restrict__ wpkD) {
    int idx = blockIdx.x * 256 + threadIdx.x;
    const int N1 = 73728, N2 = 36864, N3 = 129024, N4 = 36864;
    const float* w; unsigned short* dst; int CIN, NCF, COUT; bool asF16 = false;
    if (idx < N1)                { w = w1;   dst = wpk1; CIN = 128; NCF = 4;  COUT = 64; }
    else if (idx < N1+N2)        { idx -= N1;       w = w2;   dst = wpk2; CIN = 64; NCF = 4;  COUT = 64; }
    else if (idx < N1+N2+N3)     { idx -= N1+N2;    w = wom;  dst = wpk3; CIN = 64; NCF = 14; COUT = 216; }
    else if (idx < N1+N2+N3+N4)  { idx -= N1+N2+N3; w = wdcn; dst = wpkD; CIN = 64; NCF = 4;  COUT = 64; asF16 = true; }
    else return;
    int j    = idx & 7;
    int lane = (idx >> 3) & 63;
    int frag = idx >> 9;
    int cf   = frag % NCF;
    int ks   = frag / NCF;
    int co = cf * 16 + (lane & 15);
    int k  = ks * 32 + (lane >> 4) * 8 + j;
    int t  = k / CIN;
    int ci = k % CIN;
    float v = (co < COUT) ? w[((size_t)co * CIN + ci) * 9 + t] : 0.f;
    dst[idx] = asF16 ? f2h(v) : f2bf(v);
}

// ---------------------------------------------------------------------------
// Implicit-GEMM 3x3 conv, 64-px tiles, COUT-SPLIT waves (conv1 / conv2).
// ---------------------------------------------------------------------------
template<int CIN, int NKS, bool RELU>
__global__ __launch_bounds__(256, 3)
void conv64_mfma_kernel(const unsigned short* __restrict__ in,
                        const unsigned short* __restrict__ wpk,
                        const float* __restrict__ bias,
                        unsigned short* __restrict__ out)
{
    constexpr int ROWB = 66 * CIN * 2;
    __shared__ __align__(16) char smem[3 * ROWB];

    const int rb   = blockIdx.x;
    const int x0   = (rb & 1) * 64;
    const int y    = (rb >> 1) & 127;
    const int b    = rb >> 8;
    const int tid  = threadIdx.x;
    const int lane = tid & 63;
    const int wave = tid >> 6;
    const int l15  = lane & 15;
    const int q    = lane >> 4;
    const u32x4 zv = {0u, 0u, 0u, 0u};

    const int lstart = (x0 == 0) ? 1 : 0;
    const int lzero  = (x0 == 0) ? 0 : 65;
    for (int dy = 0; dy < 3; ++dy) {
        int yy = y + dy - 1;
        char* dstrow = smem + dy * ROWB;
        if (yy >= 0 && yy < H_DIM) {
            const char* src = (const char*)(in +
                ((size_t)(b * H_DIM + yy) * W_DIM + (x0 - 1 + lstart)) * CIN);
            for (int i = tid * 16; i < 65 * CIN * 2; i += 256 * 16)
                *(u32x4*)(dstrow + lstart * CIN * 2 + i) = *(const u32x4*)(src + i);
            if (tid < CIN / 8)
                *(u32x4*)(dstrow + lzero * CIN * 2 + tid * 16) = zv;
        } else {
            for (int i = tid * 16; i < 66 * CIN * 2; i += 256 * 16)
                *(u32x4*)(dstrow + i) = zv;
        }
    }
    __syncthreads();

    f32x4 acc[4];
#pragma unroll
    for (int pf = 0; pf < 4; ++pf)
        acc[pf] = (f32x4){0.f, 0.f, 0.f, 0.f};

#pragma unroll
    for (int ks = 0; ks < NKS; ++ks) {
        const int t   = ks / (CIN / 32);
        const int ci0 = (ks % (CIN / 32)) * 32;
        const int dy = t / 3, dx = t % 3;
        const int u  = (ci0 >> 3) + q;
        bf16x8 a[4];
#pragma unroll
        for (int pf = 0; pf < 4; ++pf) {
            const int l = pf * 16 + l15 + dx;
            const int upos = u ^ (l & 7);
            a[pf] = *(const bf16x8*)(smem + dy * ROWB + (l * CIN + upos * 8) * 2);
        }
        bf16x8 wfr = *(const bf16x8*)(wpk + ((size_t)(ks * 4 + wave) * 64 + lane) * 8);
#pragma unroll
        for (int pf = 0; pf < 4; ++pf)
            acc[pf] = __builtin_amdgcn_mfma_f32_16x16x32_bf16(a[pf], wfr, acc[pf], 0, 0, 0);
    }

    const int co = wave * 16 + l15;
    const float bv = bias[co];
#pragma unroll
    for (int pf = 0; pf < 4; ++pf)
#pragma unroll
        for (int r = 0; r < 4; ++r) {
            int x = x0 + pf * 16 + q * 4 + r;
            float v = acc[pf][r] + bv;
            if (RELU) v = (v >= 0.f) ? v : 0.1f * v;
            int cpos = (((co >> 3) ^ ((x + 1) & 7)) << 3) | (co & 7);
            out[((size_t)(b * H_DIM + y) * W_DIM + x) * 64 + cpos] = f2bf(v);
        }
}

// ---------------------------------------------------------------------------
// conv3 (216 couts) -> om bf16 [B][216][HW]. 32-px blocks (grid 2048) for
// 2x occupancy vs 64-px: acc[2][4] = 32 AGPR, om LDS [216][48] = 20.7 KB
// (staging 13 KB aliases it) -> 7 blocks/CU by LDS, 8 by grid.
// ---------------------------------------------------------------------------
__global__ __launch_bounds__(256, 4)
void conv3om_kernel(const unsigned short* __restrict__ in,   // c2o swizzled NHWC
                    const unsigned short* __restrict__ wpk3, // [18][14][64][8]
                    const float* __restrict__ bom,
                    unsigned short* __restrict__ omg)        // bf16 [B][216][HW]
{
    constexpr int ROWB = 34 * 64 * 2;          // 4352 B per dy staging row
    constexpr int OMST = 48;
    __shared__ __align__(16) char smem[216 * OMST * 2];   // 20736 B
    unsigned short* om_lds = (unsigned short*)smem;

    const int rb   = blockIdx.x;        // ((b*H + y)<<2) | quarter
    const int x0   = (rb & 3) * 32;
    const int y    = (rb >> 2) & 127;
    const int b    = rb >> 9;
    const int tid  = threadIdx.x;
    const int lane = tid & 63;
    const int wave = tid >> 6;
    const int l15  = lane & 15;
    const int q    = lane >> 4;
    const u32x4 zv = {0u, 0u, 0u, 0u};

    // ---- stage c2o rows y-1..y+1, cols x0-1..x0+32 ----
    {
        const int c0 = (x0 == 0) ? 1 : 0;
        const int c1 = (x0 == 96) ? 33 : 34;
        const int nbytes = (c1 - c0) * 128;
        for (int dy = 0; dy < 3; ++dy) {
            int yy = y + dy - 1;
            char* dstrow = smem + dy * ROWB;
            if (yy >= 0 && yy < H_DIM) {
                const char* src = (const char*)(in +
                    ((size_t)(b * H_DIM + yy) * W_DIM + (x0 - 1 + c0)) * 64);
                for (int i = tid * 16; i < nbytes; i += 256 * 16)
                    *(u32x4*)(dstrow + c0 * 128 + i) = *(const u32x4*)(src + i);
                if (x0 == 0 && tid < 8)
                    *(u32x4*)(dstrow + 0 * 128 + tid * 16) = zv;
                if (x0 == 96 && tid < 8)
                    *(u32x4*)(dstrow + 33 * 128 + tid * 16) = zv;
            } else {
                for (int i = tid * 16; i < 34 * 128; i += 256 * 16)
                    *(u32x4*)(dstrow + i) = zv;
            }
        }
    }
    __syncthreads();

    // ---- conv3: wave w -> cf {w,w+4,w+8,w+12}, 32 px ----
    f32x4 acc[2][4];
#pragma unroll
    for (int pf = 0; pf < 2; ++pf)
#pragma unroll
        for (int cfi = 0; cfi < 4; ++cfi)
            acc[pf][cfi] = (f32x4){0.f, 0.f, 0.f, 0.f};

#pragma unroll
    for (int ks = 0; ks < 18; ++ks) {
        const int t   = ks >> 1;
        const int ci0 = (ks & 1) * 32;
        const int dy = t / 3, dx = t % 3;
        bf16x8 a[2];
#pragma unroll
        for (int pf = 0; pf < 2; ++pf) {
            const int l = pf * 16 + l15 + dx;
            const int upos = ((ci0 >> 3) + q) ^ (l & 7);
            a[pf] = *(const bf16x8*)(smem + dy * ROWB + (l * 64 + upos * 8) * 2);
        }
#pragma unroll
        for (int cfi = 0; cfi < 4; ++cfi) {
            const int cf = wave + cfi * 4;
            if (cfi < 3 || wave < 2) {            // cf < 14 (wave-uniform)
                bf16x8 wfr = *(const bf16x8*)(wpk3 + ((size_t)(ks * 14 + cf) * 64 + lane) * 8);
                acc[0][cfi] = __builtin_amdgcn_mfma_f32_16x16x32_bf16(a[0], wfr, acc[0][cfi], 0, 0, 0);
                acc[1][cfi] = __builtin_amdgcn_mfma_f32_16x16x32_bf16(a[1], wfr, acc[1][cfi], 0, 0, 0);
            }
        }
    }
    __syncthreads();   // staging dead; om region aliases it

    // ---- om -> LDS bf16 [216][48] ----
#pragma unroll
    for (int cfi = 0; cfi < 4; ++cfi) {
        const int cf = wave + cfi * 4;
        if (cfi < 3 || wave < 2) {
            const int co = cf * 16 + l15;
            if (co < 216) {
                const float bv = bom[co];
#pragma unroll
                for (int pf = 0; pf < 2; ++pf) {
                    s16x4 pk;
#pragma unroll
                    for (int r = 0; r < 4; ++r)
                        pk[r] = (short)f2bf(acc[pf][cfi][r] + bv);
                    *(s16x4*)(om_lds + co * OMST + pf * 16 + q * 4) = pk;
                }
            }
        }
    }
    __syncthreads();

    // ---- dump LDS -> global, 16B coalesced ----
    unsigned short* dst = omg + (size_t)b * 216 * HW + y * W_DIM + x0;
    for (int i = tid; i < 216 * 4; i += 256) {
        int row = i >> 2;
        int seg = i & 3;
        u32x4 v = *(const u32x4*)(om_lds + row * OMST + seg * 8);
        *(u32x4*)(dst + (size_t)row * HW + seg * 8) = v;
    }
}

// ---------------------------------------------------------------------------
// Standalone deformable conv, TLP-maximized: 128-thread blocks (2 waves x
// 16 px), grid 2048 -> up to 16 blocks/CU = 32 waves/CU (2x R18's ceiling;
// R18 ran at 1.07 TB/s, concurrency-starved). om loads PLAIN (L2-hot from
// conv3om); nt only on out stores. F16 gathers/interp/MFMA, group-major x,
// XCD swizzle, 2-slot pipeline. No LDS. VGPR cap 64 via (128,8) (R18
// measured exactly 64).
// ---------------------------------------------------------------------------
struct GSlot {
    f16x8 c00, c01, c10, c11;
    f16x2 w00, w01, w10, w11;
};

__global__ __launch_bounds__(128, 8)
void deform_mfma_kernel(const unsigned short* __restrict__ xg,  // nbr [B][8][HW][8] f16
                        const unsigned short* __restrict__ omg, // bf16 [B][216][HW]
                        const unsigned short* __restrict__ wpkD,// [18][4][64][8] f16
                        const float* __restrict__ bdcn,
                        float* __restrict__ out)
{
    const int hwid = blockIdx.x;
    const int rb   = (hwid & 7) * (BATCH * H_DIM * 4 / 8) + (hwid >> 3);

    const int x0   = (rb & 3) * 32;
    const int y    = (rb >> 2) & 127;
    const int b    = rb >> 9;
    const int tid  = threadIdx.x;
    const int lane = tid & 63;
    const int wave = tid >> 6;          // 0 or 1
    const int l15  = lane & 15;
    const int q    = lane >> 4;
    const int px0w = wave * 16;

    const unsigned short* omb = omg + (size_t)b * 216 * HW;
    const int x   = x0 + px0w + l15;
    const int pix = y * W_DIM + x;

    f32x4 acc2[4];
#pragma unroll
    for (int cf = 0; cf < 4; ++cf)
        acc2[cf] = (f32x4){0.f, 0.f, 0.f, 0.f};

    auto OMLOAD = [&](int ks, float& oy, float& ox, float& mr) {
        const int och = ((ks & 1) * 4 + q) * 9 + (ks >> 1);
        oy = bf2f(omb[(size_t)och * HW + pix]);
        ox = bf2f(omb[(size_t)(72 + och) * HW + pix]);
        mr = bf2f(omb[(size_t)(144 + och) * HW + pix]);
    };

    auto GPREP = [&](int ks, float oy, float ox, float mr, GSlot& s) {
        const int tap = ks >> 1;
        const int g   = (ks & 1) * 4 + q;
        const int dy  = tap / 3 - 1;
        const int dx  = tap % 3 - 1;
        const float mask = 1.f / (1.f + __expf(-mr));

        const float sy = oy + (float)(dy + y);
        const float sx = ox + (float)(dx + x);
        const float fy = floorf(sy);
        const float fx = floorf(sx);
        const int y0  = (int)fy;
        const int xq0 = (int)fx;
        const float ay = sy - fy;
        const float ax = sx - fx;

        const bool vy0 = (y0 >= 0) && (y0 < H_DIM);
        const bool vy1 = (y0 >= -1) && (y0 < H_DIM - 1);
        const bool vx0 = (xq0 >= 0) && (xq0 < W_DIM);
        const bool vx1 = (xq0 >= -1) && (xq0 < W_DIM - 1);

        float w00 = (1.f - ay) * (1.f - ax); if (!(vy0 && vx0)) w00 = 0.f;
        float w01 = (1.f - ay) * ax;         if (!(vy0 && vx1)) w01 = 0.f;
        float w10 = ay * (1.f - ax);         if (!(vy1 && vx0)) w10 = 0.f;
        float w11 = ay * ax;                 if (!(vy1 && vx1)) w11 = 0.f;
        w00 *= mask; w01 *= mask; w10 *= mask; w11 *= mask;
        { _Float16 h = (_Float16)w00; s.w00 = (f16x2){h, h}; }
        { _Float16 h = (_Float16)w01; s.w01 = (f16x2){h, h}; }
        { _Float16 h = (_Float16)w10; s.w10 = (f16x2){h, h}; }
        { _Float16 h = (_Float16)w11; s.w11 = (f16x2){h, h}; }

        const int iy0 = min(max(y0, 0), H_DIM - 1);
        const int iy1 = min(max(y0 + 1, 0), H_DIM - 1);
        const int ix0 = min(max(xq0, 0), W_DIM - 1);
        const int ix1 = min(max(xq0 + 1, 0), W_DIM - 1);

        const unsigned short* gb = xg + (size_t)(b * 8 + g) * HW * 8;
        s.c00 = *(const f16x8*)(gb + (size_t)(iy0 * W_DIM + ix0) * 8);
        s.c01 = *(const f16x8*)(gb + (size_t)(iy0 * W_DIM + ix1) * 8);
        s.c10 = *(const f16x8*)(gb + (size_t)(iy1 * W_DIM + ix0) * 8);
        s.c11 = *(const f16x8*)(gb + (size_t)(iy1 * W_DIM + ix1) * 8);
    };

    auto CONSUME = [&](int ks, GSlot& s) {
        f16x8 av;
        const f16x2* c00 = reinterpret_cast<const f16x2*>(&s.c00);
        const f16x2* c01 = reinterpret_cast<const f16x2*>(&s.c01);
        const f16x2* c10 = reinterpret_cast<const f16x2*>(&s.c10);
        const f16x2* c11 = reinterpret_cast<const f16x2*>(&s.c11);
        f16x2* avp = reinterpret_cast<f16x2*>(&av);
#pragma unroll
        for (int j = 0; j < 4; ++j)
            avp[j] = s.w00 * c00[j] + s.w01 * c01[j]
                   + s.w10 * c10[j] + s.w11 * c11[j];
#pragma unroll
        for (int cf = 0; cf < 4; ++cf) {
            f16x8 wfr = *(const f16x8*)(wpkD + ((size_t)(ks * 4 + cf) * 64 + lane) * 8);
            acc2[cf] = __builtin_amdgcn_mfma_f32_16x16x32_f16(av, wfr, acc2[cf], 0, 0, 0);
        }
    };

    {
        float oyA, oxA, mrA, oyB, oxB, mrB;
        GSlot GA, GB;
        OMLOAD(0, oyA, oxA, mrA);
        OMLOAD(1, oyB, oxB, mrB);
        GPREP(0, oyA, oxA, mrA, GA);
#pragma unroll
        for (int ks = 0; ks < 18; ks += 2) {
            if (ks + 2 < 18) OMLOAD(ks + 2, oyA, oxA, mrA);
            GPREP(ks + 1, oyB, oxB, mrB, GB);
            CONSUME(ks, GA);
            if (ks + 3 < 18) OMLOAD(ks + 3, oyB, oxB, mrB);
            if (ks + 2 < 18) GPREP(ks + 2, oyA, oxA, mrA, GA);
            CONSUME(ks + 1, GB);
        }
    }

#pragma unroll
    for (int cf = 0; cf < 4; ++cf) {
        const int co = cf * 16 + l15;
        const float bv = bdcn[co];
#pragma unroll
        for (int r = 0; r < 4; ++r) {
            int xs = x0 + px0w + q * 4 + r;
            __builtin_nontemporal_store(acc2[cf][r] + bv,
                out + (size_t)(b * 64 + co) * HW + y * W_DIM + xs);
        }
    }
}

// ---------------------------------------------------------------------------
// Launcher. 6 dispatches. Workspace (bytes):
//   [0, 16.8M)        in1 swizzled-NHWC bf16
//   [16.8M, 25.2M)    c1o
//   [25.2M, 33.6M)    c2o
//   [33.6M, 42.0M)    nbrg f16 group-major [B][8][HW][8]
//   [42.0M, 70.3M)    omg bf16 [B][216][HW] (28.3M)
//   [70.3M, ...)      wpk1, wpk2, wpk3, wpkD(f16)
// ---------------------------------------------------------------------------
extern "C" void kernel_launch(void* const* d_in, const int* in_sizes, int n_in,
                              void* d_out, int out_size, void* d_ws, size_t ws_size,
                              hipStream_t stream) {
    const float* nbr  = (const float*)d_in[0];
    const float* ref  = (const float*)d_in[1];
    const float* w1   = (const float*)d_in[2];
    const float* b1   = (const float*)d_in[3];
    const float* w2   = (const float*)d_in[4];
    const float* b2   = (const float*)d_in[5];
    const float* wom  = (const float*)d_in[6];
    const float* bom  = (const float*)d_in[7];
    const float* wdcn = (const float*)d_in[8];
    const float* bdcn = (const float*)d_in[9];
    float* out = (float*)d_out;
    char* W = (char*)d_ws;

    unsigned short* in1  = (unsigned short*)(W + 0);
    unsigned short* c1o  = (unsigned short*)(W + 16777216);
    unsigned short* c2o  = (unsigned short*)(W + 25165824);
    unsigned short* nbrg = (unsigned short*)(W + 33554432);
    unsigned short* omg  = (unsigned short*)(W + 41943040);
    unsigned short* wpk1 = (unsigned short*)(W + 70254592);
    unsigned short* wpk2 = (unsigned short*)(W + 70402048);
    unsigned short* wpk3 = (unsigned short*)(W + 70475776);
    unsigned short* wpkD = (unsigned short*)(W + 70733824);

    prep_nhwc_kernel<<<dim3(HW / 64, BATCH), 256, 0, stream>>>(nbr, ref, in1, nbrg);
    pack_all_kernel<<<1080, 256, 0, stream>>>(w1, w2, wom, wdcn,
                                              wpk1, wpk2, wpk3, wpkD);

    // conv1: concat(nbr,ref) 128ch -> 64, lrelu (64-px tiles, cout-split)
    conv64_mfma_kernel<128, 36, true>
        <<<dim3(BATCH * H_DIM * 2), 256, 0, stream>>>(in1, wpk1, b1, c1o);
    // conv2: 64 -> 64, lrelu
    conv64_mfma_kernel<64, 18, true>
        <<<dim3(BATCH * H_DIM * 2), 256, 0, stream>>>(c1o, wpk2, b2, c2o);

    // conv3 -> om bf16 global (32-px blocks, 2x occupancy)
    conv3om_kernel<<<dim3(BATCH * H_DIM * 4), 256, 0, stream>>>(
        c2o, wpk3, bom, omg);
    // deformable conv (128-thread blocks -> 32 waves/CU TLP)
    deform_mfma_kernel<<<dim3(BATCH * H_DIM * 4), 128, 0, stream>>>(
        nbrg, omg, wpkD, bdcn, out);
}

// Round 21
// 98.942 us; speedup vs baseline: 1.3966x; 1.3966x over previous
//
#include <hip/hip_runtime.h>
#include <hip/hip_bf16.h>
#include <math.h>

#define H_DIM 128
#define W_DIM 128
#define BATCH 4
#define HW (H_DIM * W_DIM)

typedef __attribute__((ext_vector_type(8))) short bf16x8;
typedef __attribute__((ext_vector_type(4))) short s16x4;
typedef __attribute__((ext_vector_type(4))) float f32x4;
typedef __attribute__((ext_vector_type(4))) unsigned int u32x4;
typedef _Float16 f16x2 __attribute__((ext_vector_type(2)));
typedef _Float16 f16x8 __attribute__((ext_vector_type(8)));

static __device__ __forceinline__ unsigned short f2bf(float f) {
    __hip_bfloat16 h = __float2bfloat16(f);   // RNE
    return *reinterpret_cast<unsigned short*>(&h);
}
static __device__ __forceinline__ float bf2f(unsigned short u) {
    return __uint_as_float(((unsigned int)u) << 16);
}
static __device__ __forceinline__ unsigned short f2h(float f) {
    _Float16 h = (_Float16)f;                 // RNE
    return *reinterpret_cast<unsigned short*>(&h);
}

// ---------------------------------------------------------------------------
// Build swizzled-NHWC bf16 concat input [B][H][W][128]  AND  group-major
// nbr copy [B][8g][HW][8ch] in F16 (deform path is f16).
// Swizzle: unit ut of column x stored at (ut&8) | ((ut&7) ^ ((x+1)&7)).
// ---------------------------------------------------------------------------
__global__ __launch_bounds__(256)
void prep_nhwc_kernel(const float* __restrict__ nbr, const float* __restrict__ ref,
                      unsigned short* __restrict__ dst,
                      unsigned short* __restrict__ gmaj) {
    __shared__ float s[128][65];   // 33.3 KB
    const int b  = blockIdx.y;
    const int p0 = blockIdx.x * 64;
    const int t  = threadIdx.x;
    const int px = t & 63;
#pragma unroll
    for (int it = 0; it < 32; ++it) {
        int c = it * 4 + (t >> 6);
        const float* src = (c < 64) ? nbr : ref;
        int cs = c & 63;
        s[c][px] = src[(size_t)(b * 64 + cs) * HW + p0 + px];
    }
    __syncthreads();
#pragma unroll
    for (int it = 0; it < 4; ++it) {
        int idx = it * 256 + t;
        int p  = idx >> 4;
        int ut = idx & 15;
        int x  = (p0 + p) & 127;
        int key = (x + 1) & 7;
        int cpos = (ut & 8) | ((ut & 7) ^ key);
        bf16x8 v;
#pragma unroll
        for (int j = 0; j < 8; ++j)
            v[j] = (short)f2bf(s[ut * 8 + j][p]);
        *(bf16x8*)(dst + ((size_t)(b * HW + p0 + p) * 128 + cpos * 8)) = v;
    }
#pragma unroll
    for (int it = 0; it < 2; ++it) {
        int idx = it * 256 + t;
        int g   = idx >> 6;
        int p2  = idx & 63;
        bf16x8 v;
#pragma unroll
        for (int j = 0; j < 8; ++j)
            v[j] = (short)f2h(s[g * 8 + j][p2]);     // f16!
        *(bf16x8*)(gmaj + ((size_t)(b * 8 + g) * HW + p0 + p2) * 8) = v;
    }
}

// ---------------------------------------------------------------------------
// ALL weight packs in one launch. wpkD is packed as F16 (deform path);
// the rest stay bf16.
// ---------------------------------------------------------------------------
__global__ void pack_all_kernel(const float* __restrict__ w1, const float* __restrict__ w2,
                                const float* __restrict__ wom, const float* __restrict__ wdcn,
                                unsigned short* __restrict__ wpk1, unsigned short* __restrict__ wpk2,
                                unsigned short* __restrict__ wpk3, unsigned short* __restrict__ wpkD) {
    int idx = blockIdx.x * 256 + threadIdx.x;
    const int N1 = 73728, N2 = 36864, N3 = 129024, N4 = 36864;
    const float* w; unsigned short* dst; int CIN, NCF, COUT; bool asF16 = false;
    if (idx < N1)                { w = w1;   dst = wpk1; CIN = 128; NCF = 4;  COUT = 64; }
    else if (idx < N1+N2)        { idx -= N1;       w = w2;   dst = wpk2; CIN = 64; NCF = 4;  COUT = 64; }
    else if (idx < N1+N2+N3)     { idx -= N1+N2;    w = wom;  dst = wpk3; CIN = 64; NCF = 14; COUT = 216; }
    else if (idx < N1+N2+N3+N4)  { idx -= N1+N2+N3; w = wdcn; dst = wpkD; CIN = 64; NCF = 4;  COUT = 64; asF16 = true; }
    else return;
    int j    = idx & 7;
    int lane = (idx >> 3) & 63;
    int frag = idx >> 9;
    int cf   = frag % NCF;
    int ks   = frag / NCF;
    int co = cf * 16 + (lane & 15);
    int k  = ks * 32 + (lane >> 4) * 8 + j;
    int t  = k / CIN;
    int ci = k % CIN;
    float v = (co < COUT) ? w[((size_t)co * CIN + ci) * 9 + t] : 0.f;
    dst[idx] = asF16 ? f2h(v) : f2bf(v);
}

// ---------------------------------------------------------------------------
// Implicit-GEMM 3x3 conv, 64-px tiles, COUT-SPLIT waves (conv1 / conv2).
// ---------------------------------------------------------------------------
template<int CIN, int NKS, bool RELU>
__global__ __launch_bounds__(256, 3)
void conv64_mfma_kernel(const unsigned short* __restrict__ in,
                        const unsigned short* __restrict__ wpk,
                        const float* __restrict__ bias,
                        unsigned short* __restrict__ out)
{
    constexpr int ROWB = 66 * CIN * 2;
    __shared__ __align__(16) char smem[3 * ROWB];

    const int rb   = blockIdx.x;
    const int x0   = (rb & 1) * 64;
    const int y    = (rb >> 1) & 127;
    const int b    = rb >> 8;
    const int tid  = threadIdx.x;
    const int lane = tid & 63;
    const int wave = tid >> 6;
    const int l15  = lane & 15;
    const int q    = lane >> 4;
    const u32x4 zv = {0u, 0u, 0u, 0u};

    const int lstart = (x0 == 0) ? 1 : 0;
    const int lzero  = (x0 == 0) ? 0 : 65;
    for (int dy = 0; dy < 3; ++dy) {
        int yy = y + dy - 1;
        char* dstrow = smem + dy * ROWB;
        if (yy >= 0 && yy < H_DIM) {
            const char* src = (const char*)(in +
                ((size_t)(b * H_DIM + yy) * W_DIM + (x0 - 1 + lstart)) * CIN);
            for (int i = tid * 16; i < 65 * CIN * 2; i += 256 * 16)
                *(u32x4*)(dstrow + lstart * CIN * 2 + i) = *(const u32x4*)(src + i);
            if (tid < CIN / 8)
                *(u32x4*)(dstrow + lzero * CIN * 2 + tid * 16) = zv;
        } else {
            for (int i = tid * 16; i < 66 * CIN * 2; i += 256 * 16)
                *(u32x4*)(dstrow + i) = zv;
        }
    }
    __syncthreads();

    f32x4 acc[4];
#pragma unroll
    for (int pf = 0; pf < 4; ++pf)
        acc[pf] = (f32x4){0.f, 0.f, 0.f, 0.f};

#pragma unroll
    for (int ks = 0; ks < NKS; ++ks) {
        const int t   = ks / (CIN / 32);
        const int ci0 = (ks % (CIN / 32)) * 32;
        const int dy = t / 3, dx = t % 3;
        const int u  = (ci0 >> 3) + q;
        bf16x8 a[4];
#pragma unroll
        for (int pf = 0; pf < 4; ++pf) {
            const int l = pf * 16 + l15 + dx;
            const int upos = u ^ (l & 7);
            a[pf] = *(const bf16x8*)(smem + dy * ROWB + (l * CIN + upos * 8) * 2);
        }
        bf16x8 wfr = *(const bf16x8*)(wpk + ((size_t)(ks * 4 + wave) * 64 + lane) * 8);
#pragma unroll
        for (int pf = 0; pf < 4; ++pf)
            acc[pf] = __builtin_amdgcn_mfma_f32_16x16x32_bf16(a[pf], wfr, acc[pf], 0, 0, 0);
    }

    const int co = wave * 16 + l15;
    const float bv = bias[co];
#pragma unroll
    for (int pf = 0; pf < 4; ++pf)
#pragma unroll
        for (int r = 0; r < 4; ++r) {
            int x = x0 + pf * 16 + q * 4 + r;
            float v = acc[pf][r] + bv;
            if (RELU) v = (v >= 0.f) ? v : 0.1f * v;
            int cpos = (((co >> 3) ^ ((x + 1) & 7)) << 3) | (co & 7);
            out[((size_t)(b * H_DIM + y) * W_DIM + x) * 64 + cpos] = f2bf(v);
        }
}

// ---------------------------------------------------------------------------
// FUSED conv3 + deformable conv, 32-px blocks (grid 2048), K-split phase 2.
// Deform path FULLY F16 — corners gathered as f16x8, bilinear interp via
// half2 packed FMA (v_pk_fma_f16; output IS the MFMA A-fragment: no unpack
// shifts, no repack), mfma_f32_16x16x32_f16. Best measured config (R16).
// ---------------------------------------------------------------------------
struct GSlot {
    f16x8 c00, c01, c10, c11;
    f16x2 w00, w01, w10, w11;
};

__global__ __launch_bounds__(256, 4)
void fused_om_deform_kernel(const unsigned short* __restrict__ in,   // c2o swizzled NHWC
                            const unsigned short* __restrict__ xg,   // nbr [B][8][HW][8] f16
                            const unsigned short* __restrict__ wpk3, // [18][14][64][8] bf16
                            const unsigned short* __restrict__ wpkD, // [18][4][64][8] f16
                            const float* __restrict__ bom,
                            const float* __restrict__ bdcn,
                            float* __restrict__ out)
{
    constexpr int ROWB = 34 * 64 * 2;          // 4352 B per dy staging row
    constexpr int OMST = 48;                   // om LDS stride in shorts
    __shared__ __align__(16) char smem[216 * OMST * 2 + 2 * 64 * 20 * 4];
    unsigned short* om_lds = (unsigned short*)smem;
    float* red = (float*)(smem + 216 * OMST * 2);   // [2][64][20]

    const int hwid = blockIdx.x;
    const int rb   = (hwid & 7) * (BATCH * H_DIM * 4 / 8) + (hwid >> 3);
    const int x0   = (rb & 3) * 32;
    const int y    = (rb >> 2) & 127;
    const int b    = rb >> 9;
    const int tid  = threadIdx.x;
    const int lane = tid & 63;
    const int wave = tid >> 6;
    const int l15  = lane & 15;
    const int q    = lane >> 4;
    const u32x4 zv = {0u, 0u, 0u, 0u};

    // ---- phase 1a: stage c2o rows y-1..y+1, cols x0-1..x0+32 ----
    {
        const int c0 = (x0 == 0) ? 1 : 0;
        const int c1 = (x0 == 96) ? 33 : 34;
        const int nbytes = (c1 - c0) * 128;
        for (int dy = 0; dy < 3; ++dy) {
            int yy = y + dy - 1;
            char* dstrow = smem + dy * ROWB;
            if (yy >= 0 && yy < H_DIM) {
                const char* src = (const char*)(in +
                    ((size_t)(b * H_DIM + yy) * W_DIM + (x0 - 1 + c0)) * 64);
                for (int i = tid * 16; i < nbytes; i += 256 * 16)
                    *(u32x4*)(dstrow + c0 * 128 + i) = *(const u32x4*)(src + i);
                if (x0 == 0 && tid < 8)
                    *(u32x4*)(dstrow + 0 * 128 + tid * 16) = zv;
                if (x0 == 96 && tid < 8)
                    *(u32x4*)(dstrow + 33 * 128 + tid * 16) = zv;
            } else {
                for (int i = tid * 16; i < 34 * 128; i += 256 * 16)
                    *(u32x4*)(dstrow + i) = zv;
            }
        }
    }
    __syncthreads();

    // ---- phase 1b: conv3, wave w -> cf {w,w+4,w+8,w+12}, 32 px ----
    {
        f32x4 acc[2][4];
#pragma unroll
        for (int pf = 0; pf < 2; ++pf)
#pragma unroll
            for (int cfi = 0; cfi < 4; ++cfi)
                acc[pf][cfi] = (f32x4){0.f, 0.f, 0.f, 0.f};

#pragma unroll
        for (int ks = 0; ks < 18; ++ks) {
            const int t   = ks >> 1;
            const int ci0 = (ks & 1) * 32;
            const int dy = t / 3, dx = t % 3;
            bf16x8 a[2];
#pragma unroll
            for (int pf = 0; pf < 2; ++pf) {
                const int l = pf * 16 + l15 + dx;
                const int upos = ((ci0 >> 3) + q) ^ (l & 7);
                a[pf] = *(const bf16x8*)(smem + dy * ROWB + (l * 64 + upos * 8) * 2);
            }
#pragma unroll
            for (int cfi = 0; cfi < 4; ++cfi) {
                const int cf = wave + cfi * 4;
                if (cfi < 3 || wave < 2) {
                    bf16x8 wfr = *(const bf16x8*)(wpk3 + ((size_t)(ks * 14 + cf) * 64 + lane) * 8);
                    acc[0][cfi] = __builtin_amdgcn_mfma_f32_16x16x32_bf16(a[0], wfr, acc[0][cfi], 0, 0, 0);
                    acc[1][cfi] = __builtin_amdgcn_mfma_f32_16x16x32_bf16(a[1], wfr, acc[1][cfi], 0, 0, 0);
                }
            }
        }
        __syncthreads();

        // ---- phase 1c: om -> LDS bf16 [216][48] ----
#pragma unroll
        for (int cfi = 0; cfi < 4; ++cfi) {
            const int cf = wave + cfi * 4;
            if (cfi < 3 || wave < 2) {
                const int co = cf * 16 + l15;
                if (co < 216) {
                    const float bv = bom[co];
#pragma unroll
                    for (int pf = 0; pf < 2; ++pf) {
                        s16x4 pk;
#pragma unroll
                        for (int r = 0; r < 4; ++r)
                            pk[r] = (short)f2bf(acc[pf][cfi][r] + bv);
                        *(s16x4*)(om_lds + co * OMST + pf * 16 + q * 4) = pk;
                    }
                }
            }
        }
    }
    __syncthreads();

    // ---- phase 2: deform (f16 path), K-split waves, 2-slot pipeline ----
    const int pxgrp = wave >> 1;
    const int khalf = wave & 1;
    const int kbase = khalf * 9;
    const int px0w  = pxgrp * 16;
    const int xl    = px0w + l15;
    const int x     = x0 + xl;

    f32x4 acc2[4];
#pragma unroll
    for (int cf = 0; cf < 4; ++cf)
        acc2[cf] = (f32x4){0.f, 0.f, 0.f, 0.f};

    auto OMLOAD = [&](int i, float& oy, float& ox, float& mr) {
        const int ks  = kbase + i;
        const int och = ((ks & 1) * 4 + q) * 9 + (ks >> 1);
        oy = bf2f(om_lds[och * OMST + xl]);
        ox = bf2f(om_lds[(72 + och) * OMST + xl]);
        mr = bf2f(om_lds[(144 + och) * OMST + xl]);
    };

    auto GPREP = [&](int i, float oy, float ox, float mr, GSlot& s) {
        const int ks  = kbase + i;
        const int tap = ks >> 1;
        const int g   = (ks & 1) * 4 + q;
        const int dy  = tap / 3 - 1;
        const int dx  = tap % 3 - 1;
        const float mask = 1.f / (1.f + __expf(-mr));

        const float sy = oy + (float)(dy + y);
        const float sx = ox + (float)(dx + x);
        const float fy = floorf(sy);
        const float fx = floorf(sx);
        const int y0  = (int)fy;
        const int xq0 = (int)fx;
        const float ay = sy - fy;
        const float ax = sx - fx;

        const bool vy0 = (y0 >= 0) && (y0 < H_DIM);
        const bool vy1 = (y0 >= -1) && (y0 < H_DIM - 1);
        const bool vx0 = (xq0 >= 0) && (xq0 < W_DIM);
        const bool vx1 = (xq0 >= -1) && (xq0 < W_DIM - 1);

        float w00 = (1.f - ay) * (1.f - ax); if (!(vy0 && vx0)) w00 = 0.f;
        float w01 = (1.f - ay) * ax;         if (!(vy0 && vx1)) w01 = 0.f;
        float w10 = ay * (1.f - ax);         if (!(vy1 && vx0)) w10 = 0.f;
        float w11 = ay * ax;                 if (!(vy1 && vx1)) w11 = 0.f;
        w00 *= mask; w01 *= mask; w10 *= mask; w11 *= mask;
        { _Float16 h = (_Float16)w00; s.w00 = (f16x2){h, h}; }
        { _Float16 h = (_Float16)w01; s.w01 = (f16x2){h, h}; }
        { _Float16 h = (_Float16)w10; s.w10 = (f16x2){h, h}; }
        { _Float16 h = (_Float16)w11; s.w11 = (f16x2){h, h}; }

        const int iy0 = min(max(y0, 0), H_DIM - 1);
        const int iy1 = min(max(y0 + 1, 0), H_DIM - 1);
        const int ix0 = min(max(xq0, 0), W_DIM - 1);
        const int ix1 = min(max(xq0 + 1, 0), W_DIM - 1);

        const unsigned short* gb = xg + (size_t)(b * 8 + g) * HW * 8;
        s.c00 = *(const f16x8*)(gb + (size_t)(iy0 * W_DIM + ix0) * 8);
        s.c01 = *(const f16x8*)(gb + (size_t)(iy0 * W_DIM + ix1) * 8);
        s.c10 = *(const f16x8*)(gb + (size_t)(iy1 * W_DIM + ix0) * 8);
        s.c11 = *(const f16x8*)(gb + (size_t)(iy1 * W_DIM + ix1) * 8);
    };

    auto CONSUME = [&](int i, GSlot& s) {
        const int ks = kbase + i;
        f16x8 av;
        const f16x2* c00 = reinterpret_cast<const f16x2*>(&s.c00);
        const f16x2* c01 = reinterpret_cast<const f16x2*>(&s.c01);
        const f16x2* c10 = reinterpret_cast<const f16x2*>(&s.c10);
        const f16x2* c11 = reinterpret_cast<const f16x2*>(&s.c11);
        f16x2* avp = reinterpret_cast<f16x2*>(&av);
#pragma unroll
        for (int j = 0; j < 4; ++j)
            avp[j] = s.w00 * c00[j] + s.w01 * c01[j]
                   + s.w10 * c10[j] + s.w11 * c11[j];
#pragma unroll
        for (int cf = 0; cf < 4; ++cf) {
            f16x8 wfr = *(const f16x8*)(wpkD + ((size_t)(ks * 4 + cf) * 64 + lane) * 8);
            acc2[cf] = __builtin_amdgcn_mfma_f32_16x16x32_f16(av, wfr, acc2[cf], 0, 0, 0);
        }
    };

    {
        float oyA, oxA, mrA, oyB, oxB, mrB;
        GSlot GA, GB;
        OMLOAD(0, oyA, oxA, mrA);
        OMLOAD(1, oyB, oxB, mrB);
        GPREP(0, oyA, oxA, mrA, GA);
#pragma unroll
        for (int i = 0; i < 8; i += 2) {
            OMLOAD(i + 2, oyA, oxA, mrA);
            GPREP(i + 1, oyB, oxB, mrB, GB);
            CONSUME(i, GA);
            if (i + 3 < 9) OMLOAD(i + 3, oyB, oxB, mrB);
            GPREP(i + 2, oyA, oxA, mrA, GA);
            CONSUME(i + 1, GB);
        }
        CONSUME(8, GA);
    }

    // ---- K-split reduction ----
    if (khalf == 1) {
#pragma unroll
        for (int cf = 0; cf < 4; ++cf)
            *(f32x4*)&red[((size_t)pxgrp * 64 + lane) * 20 + cf * 4] = acc2[cf];
    }
    __syncthreads();
    if (khalf == 0) {
#pragma unroll
        for (int cf = 0; cf < 4; ++cf) {
            const f32x4 other = *(const f32x4*)&red[((size_t)pxgrp * 64 + lane) * 20 + cf * 4];
            const int co = cf * 16 + l15;
            const float bv = bdcn[co];
#pragma unroll
            for (int r = 0; r < 4; ++r) {
                int xs = x0 + px0w + q * 4 + r;
                __builtin_nontemporal_store(acc2[cf][r] + other[r] + bv,
                    out + (size_t)(b * 64 + co) * HW + y * W_DIM + xs);
            }
        }
    }
}

// ---------------------------------------------------------------------------
// Launcher. 5 dispatches. Workspace (bytes):
//   [0, 16.8M)        in1 swizzled-NHWC bf16
//   [16.8M, 25.2M)    c1o
//   [25.2M, 33.6M)    c2o
//   [33.6M, 42.0M)    nbrg f16 group-major [B][8][HW][8]
//   [42.0M, ...)      wpk1, wpk2, wpk3, wpkD(f16)
// ---------------------------------------------------------------------------
extern "C" void kernel_launch(void* const* d_in, const int* in_sizes, int n_in,
                              void* d_out, int out_size, void* d_ws, size_t ws_size,
                              hipStream_t stream) {
    const float* nbr  = (const float*)d_in[0];
    const float* ref  = (const float*)d_in[1];
    const float* w1   = (const float*)d_in[2];
    const float* b1   = (const float*)d_in[3];
    const float* w2   = (const float*)d_in[4];
    const float* b2   = (const float*)d_in[5];
    const float* wom  = (const float*)d_in[6];
    const float* bom  = (const float*)d_in[7];
    const float* wdcn = (const float*)d_in[8];
    const float* bdcn = (const float*)d_in[9];
    float* out = (float*)d_out;
    char* W = (char*)d_ws;

    unsigned short* in1  = (unsigned short*)(W + 0);
    unsigned short* c1o  = (unsigned short*)(W + 16777216);
    unsigned short* c2o  = (unsigned short*)(W + 25165824);
    unsigned short* nbrg = (unsigned short*)(W + 33554432);
    unsigned short* wpk1 = (unsigned short*)(W + 41943040);
    unsigned short* wpk2 = (unsigned short*)(W + 42090496);
    unsigned short* wpk3 = (unsigned short*)(W + 42164224);
    unsigned short* wpkD = (unsigned short*)(W + 42422272);

    prep_nhwc_kernel<<<dim3(HW / 64, BATCH), 256, 0, stream>>>(nbr, ref, in1, nbrg);
    pack_all_kernel<<<1080, 256, 0, stream>>>(w1, w2, wom, wdcn,
                                              wpk1, wpk2, wpk3, wpkD);

    // conv1: concat(nbr,ref) 128ch -> 64, lrelu (64-px tiles, cout-split)
    conv64_mfma_kernel<128, 36, true>
        <<<dim3(BATCH * H_DIM * 2), 256, 0, stream>>>(in1, wpk1, b1, c1o);
    // conv2: 64 -> 64, lrelu
    conv64_mfma_kernel<64, 18, true>
        <<<dim3(BATCH * H_DIM * 2), 256, 0, stream>>>(c1o, wpk2, b2, c2o);

    // fused conv3 + deformable conv (f16 deform path, packed-f16 interp)
    fused_om_deform_kernel<<<dim3(BATCH * H_DIM * 4), 256, 0, stream>>>(
        c2o, nbrg, wpk3, wpkD, bom, bdcn, out);
}